// Round 15
// baseline (158.769 us; speedup 1.0000x reference)
//
#include <hip/hip_runtime.h>
#include <stdint.h>

#define NROWS 8192
#define KX    2048      // N*M
#define KA    2112      // KX + NF (augmented K)
#define NF    64
#define DD    2016
#define WCOLS 2080      // NF + DD
#define ODIM  1024
#define BN_EPS 1e-5f

#define A1_OT 32
#define A2_DC 8
#define A2_DPC 252
#define A2_OT 16

#define CONV_RPB 4
#define CONV_NB  (NROWS / CONV_RPB)    // 2048
#define RED_NB   (ODIM * NF / 256)     // 256 reduce blocks folded into conv

// a1a2 grid: [0,256) a1 | [256,768) a2 | [768,776) zero-sums
#define A1A2_A1N 256
#define A1A2_A2E 768
#define A1A2_TOT 776

// GEMM geometry: 256x128 tile, BK=32, 256 thr (4 waves 2Mx2N, wave=128x64)
// 3 buffers x 24KB = 72KB LDS -> 2 blocks/CU (8 waves/CU, m114 overlap).
// Wave-tile 128x64 cuts LDS fragment reads 25% vs 64x64 (LDS-read-bound loop).
#define GBM 256
#define GBN 128
#define NT (KA / 32)    // 66 K-tiles = 3*22 (static 3-buffer rotation)

using f32x4  = __attribute__((ext_vector_type(4))) float;
using bf16x8 = __attribute__((ext_vector_type(8))) short;

__device__ __forceinline__ short f2bf(float x) {
    uint32_t u = __float_as_uint(x);
    uint32_t r = (u + 0x7FFFu + ((u >> 16) & 1u)) >> 16;   // RNE to bf16
    return (short)r;
}

__device__ __forceinline__ void gload16(const void* g, void* l) {
    __builtin_amdgcn_global_load_lds(
        (const __attribute__((address_space(1))) uint32_t*)g,
        (__attribute__((address_space(3))) uint32_t*)l, 16, 0, 0);
}

#define MFMA_BF16 __builtin_amdgcn_mfma_f32_16x16x32_bf16

// ---------------------------------------------------------------------------
// Kernel 1a: conv (2048 blocks x 4 rows) + a2_reduce (256 blocks) folded in.
// ---------------------------------------------------------------------------
__global__ __launch_bounds__(256) void conv_kern(const float* __restrict__ X,
                                                 short* __restrict__ Xa,
                                                 const float* __restrict__ partials,
                                                 short* __restrict__ Aw) {
    const int t = threadIdx.x;
    const int b = blockIdx.x;
    if (b < CONV_NB) {
#pragma unroll
        for (int r = 0; r < CONV_RPB; ++r) {
            const int row = b * CONV_RPB + r;
            const float4* xr = reinterpret_cast<const float4*>(X + (size_t)row * KX);
            float4 v0 = xr[t * 2];
            float4 v1 = xr[t * 2 + 1];
            bf16x8 s;
            s[0] = f2bf(v0.x); s[1] = f2bf(v0.y); s[2] = f2bf(v0.z); s[3] = f2bf(v0.w);
            s[4] = f2bf(v1.x); s[5] = f2bf(v1.y); s[6] = f2bf(v1.z); s[7] = f2bf(v1.w);
            short* outr = Xa + (size_t)row * KA;
            reinterpret_cast<bf16x8*>(outr)[t] = s;
            float sq = v0.x*v0.x + v0.y*v0.y + v0.z*v0.z + v0.w*v0.w
                     + v1.x*v1.x + v1.y*v1.y + v1.z*v1.z + v1.w*v1.w;
            sq += __shfl_xor(sq, 1);
            sq += __shfl_xor(sq, 2);
            if ((t & 3) == 0) outr[KX + (t >> 2)] = f2bf(sq - 32.0f);  // centered
        }
    } else {
        const int idx = (b - CONV_NB) * 256 + t;   // o*64+n
        const int o = idx >> 6, n = idx & 63;
        float s = 0.f;
#pragma unroll
        for (int c = 0; c < A2_DC; ++c)
            s += partials[((size_t)c * ODIM + o) * NF + n];
        Aw[(size_t)o * KA + KX + n] = f2bf(s);
    }
}

// ---------------------------------------------------------------------------
// Kernel 1b: a1 + a2 (LDS-staged Wa) + zero-sums blocks (memset folded in).
// ---------------------------------------------------------------------------
__global__ __launch_bounds__(256) void a1a2_kern(short* __restrict__ Aw,
                                                 const float* __restrict__ Wa,
                                                 const float* __restrict__ Wz,
                                                 const float* __restrict__ theta,
                                                 float* __restrict__ partials,
                                                 float* __restrict__ sums) {
    const int bid = blockIdx.x;
    const int t = threadIdx.x;
    __shared__ __align__(16) float smem[4096];   // 16 KB

    if (bid >= A1A2_A2E) {
        sums[(bid - A1A2_A2E) * 256 + t] = 0.f;
        return;
    }
    if (bid < A1A2_A1N) {
        const int k = (bid & 7) * 256 + t;
        const int o0 = (bid >> 3) * A1_OT;
        for (int idx = t; idx < A1_OT * 64; idx += 256)
            smem[idx] = Wa[(size_t)(o0 + (idx >> 6)) * WCOLS + (idx & 63)];
        float wz[64];
#pragma unroll
        for (int d = 0; d < 64; ++d) wz[d] = Wz[(size_t)d * KX + k];
        __syncthreads();
#pragma unroll 2
        for (int j = 0; j < A1_OT; ++j) {
            const float* war = &smem[j * 64];
            float acc = 0.f;
#pragma unroll
            for (int d = 0; d < 64; ++d) acc += war[d] * wz[d];
            Aw[(size_t)(o0 + j) * KA + k] = f2bf(acc);
        }
    } else {
        const int b = bid - A1A2_A1N;
        const int n = t & 63;
        const int g = t >> 6;
        const int chunk = b & 7;
        const int o0 = (b >> 3) * A2_OT;
        const int d0 = chunk * A2_DPC;
        float* waT = smem;                       // [A2_OT][A2_DPC] = 4032 floats
        for (int idx = t; idx < A2_OT * A2_DPC; idx += 256) {
            const int j = idx / A2_DPC, dd = idx - j * A2_DPC;
            waT[idx] = Wa[(size_t)(o0 + j) * WCOLS + NF + d0 + dd];
        }
        __syncthreads();
        float acc[A2_OT];
#pragma unroll
        for (int j = 0; j < A2_OT; ++j) acc[j] = 0.f;
        for (int i = g; i < A2_DPC; i += 4) {
            float th = theta[(size_t)(d0 + i) * NF + n];
            float th2 = th * th;
#pragma unroll
            for (int j = 0; j < A2_OT; ++j)
                acc[j] += waT[j * A2_DPC + i] * th2;
        }
        __syncthreads();                          // waT dead; reuse as red
        float* red = smem;                        // [4][A2_OT][64] = 4096
#pragma unroll
        for (int j = 0; j < A2_OT; ++j) red[(g * A2_OT + j) * 64 + n] = acc[j];
        __syncthreads();
#pragma unroll
        for (int k2 = 0; k2 < A2_OT * 64 / 256; ++k2) {
            const int idx = t + k2 * 256;
            const int ol = idx >> 6, nn = idx & 63;
            float s = red[(0 * A2_OT + ol) * 64 + nn] + red[(1 * A2_OT + ol) * 64 + nn]
                    + red[(2 * A2_OT + ol) * 64 + nn] + red[(3 * A2_OT + ol) * 64 + nn];
            partials[((size_t)chunk * ODIM + o0 + ol) * NF + nn] = s;
        }
    }
}

// ---------------------------------------------------------------------------
// Kernel 3: GEMM — 256x128 tile, BK=32, 4 waves (2Mx2N, wave-tile 128x64,
// acc[8][4]).  LDS reads/tile 96KB vs r13's 128KB (the loop is LDS-read-
// bound: 85 B/cyc b128 throughput).  3-buffer 72KB -> 2 blocks/CU (8
// waves/CU, cross-block barrier overlap).  2-tile lookahead, counted
// vmcnt(6), one raw barrier/tile.  r2-proven 4-slot XOR swizzle.
// Fused BN sums epilogue (bias cancels under BN).
// ---------------------------------------------------------------------------
__global__ __launch_bounds__(256, 2) void gemm_kern(const short* __restrict__ Xa,
                                                    const short* __restrict__ Aw,
                                                    float* __restrict__ C,
                                                    float* __restrict__ sums) {
    __shared__ __align__(16) short As[3][GBM * 32];   // 3 x 16 KB
    __shared__ __align__(16) short Bs[3][GBN * 32];   // 3 x 8 KB
    const int tid  = threadIdx.x;
    const int lane = tid & 63;
    const int cl   = lane & 15;
    const int lq   = lane >> 4;       // k-slot within fragment row
    const int wid  = tid >> 6;
    const int wr   = wid >> 1;        // 0..1 (M half: 128 rows)
    const int wc   = wid & 1;         // 0..1 (N half: 64 cols)
    const int bm = blockIdx.x * GBM;
    const int bn = blockIdx.y * GBN;

    f32x4 acc[8][4] = {};

    // Staging maps (BK=32: row = 64B = 4 chunks; chunk c: row r=c>>2,
    // slot q=(c&3)^((r>>1)&3); LDS linear dest, pre-swizzled global src).
    // A: 1024 chunks -> 4 gloads/thread; B: 512 -> 2.
    const short* gAs[4]; int ldA[4];
#pragma unroll
    for (int i = 0; i < 4; ++i) {
        const int c = tid + i * 256;            // 0..1023
        const int r = c >> 2, q = (c & 3) ^ ((r >> 1) & 3);
        gAs[i] = Xa + (size_t)(bm + r) * KA + q * 8;
        ldA[i] = c * 8;
    }
    const short* gBs[2]; int ldB[2];
#pragma unroll
    for (int i = 0; i < 2; ++i) {
        const int c = tid + i * 256;            // 0..511
        const int r = c >> 2, q = (c & 3) ^ ((r >> 1) & 3);
        gBs[i] = Aw + (size_t)(bn + r) * KA + q * 8;
        ldB[i] = c * 8;
    }

    // Swizzled LDS read offsets (shorts); row stride 32 shorts.
    int offA[8], offB[4];
#pragma unroll
    for (int m = 0; m < 8; ++m) {
        const int r = wr * 128 + m * 16 + cl;
        offA[m] = r * 32 + (lq ^ ((r >> 1) & 3)) * 8;
    }
#pragma unroll
    for (int n = 0; n < 4; ++n) {
        const int r = wc * 64 + n * 16 + cl;
        offB[n] = r * 32 + (lq ^ ((r >> 1) & 3)) * 8;
    }

#define STAGE(buf, kt) do {                               \
        const int ko_ = (kt) * 32;                        \
        gload16(gAs[0] + ko_, &As[buf][ldA[0]]);          \
        gload16(gAs[1] + ko_, &As[buf][ldA[1]]);          \
        gload16(gAs[2] + ko_, &As[buf][ldA[2]]);          \
        gload16(gAs[3] + ko_, &As[buf][ldA[3]]);          \
        gload16(gBs[0] + ko_, &Bs[buf][ldB[0]]);          \
        gload16(gBs[1] + ko_, &Bs[buf][ldB[1]]);          \
    } while (0)

#define TILE(cbuf, sbuf, kt) do {                                            \
        if ((kt) + 2 < NT) STAGE(sbuf, (kt) + 2);                            \
        bf16x8 a_[8], b_[4];                                                 \
        _Pragma("unroll")                                                    \
        for (int m = 0; m < 8; ++m)                                          \
            a_[m] = *reinterpret_cast<const bf16x8*>(&As[cbuf][offA[m]]);    \
        _Pragma("unroll")                                                    \
        for (int n = 0; n < 4; ++n)                                          \
            b_[n] = *reinterpret_cast<const bf16x8*>(&Bs[cbuf][offB[n]]);    \
        asm volatile("s_waitcnt lgkmcnt(0)" ::: "memory");                   \
        __builtin_amdgcn_sched_barrier(0);                                   \
        __builtin_amdgcn_s_setprio(1);                                       \
        _Pragma("unroll")                                                    \
        for (int m = 0; m < 8; ++m)                                          \
            _Pragma("unroll")                                                \
            for (int n = 0; n < 4; ++n)                                      \
                acc[m][n] = MFMA_BF16(a_[m], b_[n], acc[m][n], 0, 0, 0);     \
        __builtin_amdgcn_s_setprio(0);                                       \
        if ((kt) + 2 < NT)                                                   \
            asm volatile("s_waitcnt vmcnt(6)" ::: "memory");                 \
        else if ((kt) + 1 < NT)                                              \
            asm volatile("s_waitcnt vmcnt(0)" ::: "memory");                 \
        __builtin_amdgcn_s_barrier();                                        \
    } while (0)

    // prologue: stage tiles 0,1 (12 gloads); wait tile 0 (oldest 6)
    STAGE(0, 0);
    STAGE(1, 1);
    asm volatile("s_waitcnt vmcnt(6)" ::: "memory");
    __builtin_amdgcn_s_barrier();

    for (int kt = 0; kt < NT; kt += 3) {     // NT = 66 = 3*22
        TILE(0, 2, kt);
        TILE(1, 0, kt + 1);
        TILE(2, 1, kt + 2);
    }
#undef TILE
#undef STAGE

    // Epilogue: store C (pre-BN) + fused column sum/sumsq partials.
    // C/D layout col=lane&15, row=(lane>>4)*4+reg (m89/m91 verified).
    const int rlo = lq * 4;
#pragma unroll
    for (int n = 0; n < 4; ++n) {
        const int col = bn + wc * 64 + n * 16 + cl;
        float s = 0.f, q = 0.f;
#pragma unroll
        for (int m = 0; m < 8; ++m) {
            const int rowb = bm + wr * 128 + m * 16 + rlo;
#pragma unroll
            for (int r2 = 0; r2 < 4; ++r2) {
                float v = acc[m][n][r2];
                C[(size_t)(rowb + r2) * ODIM + col] = v;
                s += v; q += v * v;
            }
        }
        s += __shfl_xor(s, 16); s += __shfl_xor(s, 32);
        q += __shfl_xor(q, 16); q += __shfl_xor(q, 32);
        if (lane < 16) {
            atomicAdd(&sums[col], s);
            atomicAdd(&sums[ODIM + col], q);
        }
    }
}

// ---------------------------------------------------------------------------
// Kernel 4: BN apply with inline finalize (2048 blocks, 4 rows/thread).
// ---------------------------------------------------------------------------
__global__ __launch_bounds__(256) void bn_apply(float* __restrict__ C,
                                                const float* __restrict__ sums,
                                                const float* __restrict__ gamma,
                                                const float* __restrict__ beta) {
    const int g = blockIdx.x * 256 + threadIdx.x;
    const int c4 = g & (ODIM / 4 - 1);
    const int row0 = g >> 8;                        // 0..2047
    const float inv = 1.0f / (float)NROWS;
    float4 sc, sh;
    {
        float4 s0 = reinterpret_cast<const float4*>(sums)[c4];
        float4 q0 = reinterpret_cast<const float4*>(sums + ODIM)[c4];
        float4 gm = reinterpret_cast<const float4*>(gamma)[c4];
        float4 bt = reinterpret_cast<const float4*>(beta)[c4];
        float m, v;
        m = s0.x * inv; v = q0.x * inv - m * m; sc.x = gm.x * rsqrtf(v + BN_EPS); sh.x = bt.x - m * sc.x;
        m = s0.y * inv; v = q0.y * inv - m * m; sc.y = gm.y * rsqrtf(v + BN_EPS); sh.y = bt.y - m * sc.y;
        m = s0.z * inv; v = q0.z * inv - m * m; sc.z = gm.z * rsqrtf(v + BN_EPS); sh.z = bt.z - m * sc.z;
        m = s0.w * inv; v = q0.w * inv - m * m; sc.w = gm.w * rsqrtf(v + BN_EPS); sh.w = bt.w - m * sc.w;
    }
#pragma unroll
    for (int r = 0; r < 4; ++r) {
        const size_t i = (size_t)(row0 + r * 2048) * (ODIM / 4) + c4;
        float4 v = reinterpret_cast<const float4*>(C)[i];
        v.x = v.x * sc.x + sh.x;
        v.y = v.y * sc.y + sh.y;
        v.z = v.z * sc.z + sh.z;
        v.w = v.w * sc.w + sh.w;
        reinterpret_cast<float4*>(C)[i] = v;
    }
}

// ---------------------------------------------------------------------------
extern "C" void kernel_launch(void* const* d_in, const int* in_sizes, int n_in,
                              void* d_out, int out_size, void* d_ws, size_t ws_size,
                              hipStream_t stream) {
    const float* X     = (const float*)d_in[0];
    const float* Wz    = (const float*)d_in[1];
    const float* theta = (const float*)d_in[2];
    const float* Wa    = (const float*)d_in[3];
    const float* gamma = (const float*)d_in[5];
    const float* beta  = (const float*)d_in[6];
    float* out = (float*)d_out;

    char* ws = (char*)d_ws;
    float* sums = (float*)ws;                                        // 2*1024 f32
    short* Xa = (short*)(ws + 16384);                                // 8192*2112 bf16
    short* Aw = (short*)(ws + 16384 + (size_t)NROWS * KA * 2);       // 1024*2112 bf16
    float* partials = (float*)(ws + 16384 + (size_t)NROWS * KA * 2
                                        + (size_t)ODIM * KA * 2);    // 8*1024*64 f32

    a1a2_kern<<<A1A2_TOT, 256, 0, stream>>>(Aw, Wa, Wz, theta, partials, sums);
    conv_kern<<<CONV_NB + RED_NB, 256, 0, stream>>>(X, Xa, partials, Aw);
    gemm_kern<<<dim3(NROWS / GBM, ODIM / GBN), 256, 0, stream>>>(Xa, Aw, out, sums);
    bn_apply<<<NROWS / 4 * ODIM / 4 / 256, 256, 0, stream>>>(out, sums, gamma, beta);
}

// Round 16
// 100.562 us; speedup vs baseline: 1.5788x; 1.5788x over previous
//
#include <hip/hip_runtime.h>
#include <stdint.h>

#define NROWS 8192
#define KX    2048      // N*M
#define KA    2112      // KX + NF (augmented K)
#define NF    64
#define DD    2016
#define WCOLS 2080      // NF + DD
#define ODIM  1024
#define BN_EPS 1e-5f

#define A1_OT 32
#define A2_DC 8
#define A2_DPC 252
#define A2_OT 16

#define CONV_RPB 4
#define CONV_NB  (NROWS / CONV_RPB)    // 2048
#define RED_NB   (ODIM * NF / 256)     // 256 reduce blocks folded into conv

// a1a2 grid: [0,256) a1 | [256,768) a2 | [768,776) zero-sums
#define A1A2_A1N 256
#define A1A2_A2E 768
#define A1A2_TOT 776

// GEMM geometry: 256x128 tile, BK=64, 512 thr (8 waves 4Mx2N), grid 32x8=256
#define GBM 256
#define GBN 128
#define GBK 64
#define NT (KA / GBK)   // 33 K-tiles = 3*11 (static 3-buffer rotation)

using f32x4  = __attribute__((ext_vector_type(4))) float;
using bf16x8 = __attribute__((ext_vector_type(8))) short;

__device__ __forceinline__ short f2bf(float x) {
    uint32_t u = __float_as_uint(x);
    uint32_t r = (u + 0x7FFFu + ((u >> 16) & 1u)) >> 16;   // RNE to bf16
    return (short)r;
}

__device__ __forceinline__ void gload16(const void* g, void* l) {
    __builtin_amdgcn_global_load_lds(
        (const __attribute__((address_space(1))) uint32_t*)g,
        (__attribute__((address_space(3))) uint32_t*)l, 16, 0, 0);
}

#define MFMA_BF16 __builtin_amdgcn_mfma_f32_16x16x32_bf16

// ---------------------------------------------------------------------------
// Kernel 1a: conv (2048 blocks x 4 rows) + a2_reduce (256 blocks) folded in.
// ---------------------------------------------------------------------------
__global__ __launch_bounds__(256) void conv_kern(const float* __restrict__ X,
                                                 short* __restrict__ Xa,
                                                 const float* __restrict__ partials,
                                                 short* __restrict__ Aw) {
    const int t = threadIdx.x;
    const int b = blockIdx.x;
    if (b < CONV_NB) {
#pragma unroll
        for (int r = 0; r < CONV_RPB; ++r) {
            const int row = b * CONV_RPB + r;
            const float4* xr = reinterpret_cast<const float4*>(X + (size_t)row * KX);
            float4 v0 = xr[t * 2];
            float4 v1 = xr[t * 2 + 1];
            bf16x8 s;
            s[0] = f2bf(v0.x); s[1] = f2bf(v0.y); s[2] = f2bf(v0.z); s[3] = f2bf(v0.w);
            s[4] = f2bf(v1.x); s[5] = f2bf(v1.y); s[6] = f2bf(v1.z); s[7] = f2bf(v1.w);
            short* outr = Xa + (size_t)row * KA;
            reinterpret_cast<bf16x8*>(outr)[t] = s;
            float sq = v0.x*v0.x + v0.y*v0.y + v0.z*v0.z + v0.w*v0.w
                     + v1.x*v1.x + v1.y*v1.y + v1.z*v1.z + v1.w*v1.w;
            sq += __shfl_xor(sq, 1);
            sq += __shfl_xor(sq, 2);
            if ((t & 3) == 0) outr[KX + (t >> 2)] = f2bf(sq - 32.0f);  // centered
        }
    } else {
        const int idx = (b - CONV_NB) * 256 + t;   // o*64+n
        const int o = idx >> 6, n = idx & 63;
        float s = 0.f;
#pragma unroll
        for (int c = 0; c < A2_DC; ++c)
            s += partials[((size_t)c * ODIM + o) * NF + n];
        Aw[(size_t)o * KA + KX + n] = f2bf(s);
    }
}

// ---------------------------------------------------------------------------
// Kernel 1b: a1 + a2 (LDS-staged Wa) + zero-sums blocks (memset folded in).
// ---------------------------------------------------------------------------
__global__ __launch_bounds__(256) void a1a2_kern(short* __restrict__ Aw,
                                                 const float* __restrict__ Wa,
                                                 const float* __restrict__ Wz,
                                                 const float* __restrict__ theta,
                                                 float* __restrict__ partials,
                                                 float* __restrict__ sums) {
    const int bid = blockIdx.x;
    const int t = threadIdx.x;
    __shared__ __align__(16) float smem[4096];   // 16 KB

    if (bid >= A1A2_A2E) {
        sums[(bid - A1A2_A2E) * 256 + t] = 0.f;
        return;
    }
    if (bid < A1A2_A1N) {
        const int k = (bid & 7) * 256 + t;
        const int o0 = (bid >> 3) * A1_OT;
        for (int idx = t; idx < A1_OT * 64; idx += 256)
            smem[idx] = Wa[(size_t)(o0 + (idx >> 6)) * WCOLS + (idx & 63)];
        float wz[64];
#pragma unroll
        for (int d = 0; d < 64; ++d) wz[d] = Wz[(size_t)d * KX + k];
        __syncthreads();
#pragma unroll 2
        for (int j = 0; j < A1_OT; ++j) {
            const float* war = &smem[j * 64];
            float acc = 0.f;
#pragma unroll
            for (int d = 0; d < 64; ++d) acc += war[d] * wz[d];
            Aw[(size_t)(o0 + j) * KA + k] = f2bf(acc);
        }
    } else {
        const int b = bid - A1A2_A1N;
        const int n = t & 63;
        const int g = t >> 6;
        const int chunk = b & 7;
        const int o0 = (b >> 3) * A2_OT;
        const int d0 = chunk * A2_DPC;
        float* waT = smem;                       // [A2_OT][A2_DPC] = 4032 floats
        for (int idx = t; idx < A2_OT * A2_DPC; idx += 256) {
            const int j = idx / A2_DPC, dd = idx - j * A2_DPC;
            waT[idx] = Wa[(size_t)(o0 + j) * WCOLS + NF + d0 + dd];
        }
        __syncthreads();
        float acc[A2_OT];
#pragma unroll
        for (int j = 0; j < A2_OT; ++j) acc[j] = 0.f;
        for (int i = g; i < A2_DPC; i += 4) {
            float th = theta[(size_t)(d0 + i) * NF + n];
            float th2 = th * th;
#pragma unroll
            for (int j = 0; j < A2_OT; ++j)
                acc[j] += waT[j * A2_DPC + i] * th2;
        }
        __syncthreads();                          // waT dead; reuse as red
        float* red = smem;                        // [4][A2_OT][64] = 4096
#pragma unroll
        for (int j = 0; j < A2_OT; ++j) red[(g * A2_OT + j) * 64 + n] = acc[j];
        __syncthreads();
#pragma unroll
        for (int k2 = 0; k2 < A2_OT * 64 / 256; ++k2) {
            const int idx = t + k2 * 256;
            const int ol = idx >> 6, nn = idx & 63;
            float s = red[(0 * A2_OT + ol) * 64 + nn] + red[(1 * A2_OT + ol) * 64 + nn]
                    + red[(2 * A2_OT + ol) * 64 + nn] + red[(3 * A2_OT + ol) * 64 + nn];
            partials[((size_t)chunk * ODIM + o0 + ol) * NF + nn] = s;
        }
    }
}

// ---------------------------------------------------------------------------
// Kernel 3: GEMM — r13 verbatim (256x128, BK=64, 512 thr, 3-buffer,
// counted vmcnt(6), one raw barrier/tile, 8-slot XOR swizzle) with ONE
// change: the manual lgkmcnt(0)+sched_barrier drain before the MFMA
// cluster is removed — compiler emits fine-grained lgkmcnt(N) per
// fragment (m97 evidence), so early MFMAs overlap late ds_reads.
// ---------------------------------------------------------------------------
__global__ __launch_bounds__(512) void gemm_kern(const short* __restrict__ Xa,
                                                 const short* __restrict__ Aw,
                                                 float* __restrict__ C,
                                                 float* __restrict__ sums) {
    __shared__ __align__(16) short As[3][GBM * GBK];   // 3 x 32 KB
    __shared__ __align__(16) short Bs[3][GBN * GBK];   // 3 x 16 KB
    const int tid  = threadIdx.x;
    const int lane = tid & 63;
    const int cl   = lane & 15;
    const int kq   = lane >> 4;       // k-quarter within fragment
    const int wid  = tid >> 6;
    const int wr   = wid >> 1;        // 0..3 (M)
    const int wc   = wid & 1;         // 0..1 (N)
    const int bm = blockIdx.x * GBM;
    const int bn = blockIdx.y * GBN;

    f32x4 acc[4][4] = {};

    // Staging maps (16B chunk c: row = c>>3, slot cp = c&7; LDS linear,
    // global col-chunk = cp ^ (row&7) — inverse of the read swizzle).
    const short* gAs[4]; int ldA[4];
#pragma unroll
    for (int i = 0; i < 4; ++i) {
        const int c = tid + i * 512;            // 0..2047
        const int row = c >> 3, cp = c & 7;
        gAs[i] = Xa + (size_t)(bm + row) * KA + (cp ^ (row & 7)) * 8;
        ldA[i] = c * 8;
    }
    const short* gBs[2]; int ldB[2];
#pragma unroll
    for (int i = 0; i < 2; ++i) {
        const int c = tid + i * 512;            // 0..1023
        const int row = c >> 3, cp = c & 7;
        gBs[i] = Aw + (size_t)(bn + row) * KA + (cp ^ (row & 7)) * 8;
        ldB[i] = c * 8;
    }

    // Swizzled LDS read offsets (shorts); row stride = GBK = 64 shorts.
    int offA[4][2], offB[4][2];
#pragma unroll
    for (int m = 0; m < 4; ++m) {
        const int r = wr * 64 + m * 16 + cl;
        offA[m][0] = r * GBK + ((kq)     ^ (r & 7)) * 8;
        offA[m][1] = r * GBK + ((4 + kq) ^ (r & 7)) * 8;
    }
#pragma unroll
    for (int n = 0; n < 4; ++n) {
        const int r = wc * 64 + n * 16 + cl;
        offB[n][0] = r * GBK + ((kq)     ^ (r & 7)) * 8;
        offB[n][1] = r * GBK + ((4 + kq) ^ (r & 7)) * 8;
    }

#define STAGE(buf, kt) do {                               \
        const int ko_ = (kt) * GBK;                       \
        gload16(gAs[0] + ko_, &As[buf][ldA[0]]);          \
        gload16(gAs[1] + ko_, &As[buf][ldA[1]]);          \
        gload16(gAs[2] + ko_, &As[buf][ldA[2]]);          \
        gload16(gAs[3] + ko_, &As[buf][ldA[3]]);          \
        gload16(gBs[0] + ko_, &Bs[buf][ldB[0]]);          \
        gload16(gBs[1] + ko_, &Bs[buf][ldB[1]]);          \
    } while (0)

    // TILE: compute tile kt from cbuf, prefetch kt+2 into sbuf; counted
    // vmcnt keeps kt+2's 6 loads in flight across the single barrier.
    // No manual lgkmcnt drain: register data-deps give the compiler's own
    // fine-grained lgkmcnt(N) interleave of ds_read with early MFMAs.
#define TILE(cbuf, sbuf, kt) do {                                            \
        if ((kt) + 2 < NT) STAGE(sbuf, (kt) + 2);                            \
        bf16x8 a_[4][2], b_[4][2];                                           \
        _Pragma("unroll")                                                    \
        for (int m = 0; m < 4; ++m) {                                        \
            a_[m][0] = *reinterpret_cast<const bf16x8*>(&As[cbuf][offA[m][0]]); \
            a_[m][1] = *reinterpret_cast<const bf16x8*>(&As[cbuf][offA[m][1]]); \
        }                                                                    \
        _Pragma("unroll")                                                    \
        for (int n = 0; n < 4; ++n) {                                        \
            b_[n][0] = *reinterpret_cast<const bf16x8*>(&Bs[cbuf][offB[n][0]]); \
            b_[n][1] = *reinterpret_cast<const bf16x8*>(&Bs[cbuf][offB[n][1]]); \
        }                                                                    \
        __builtin_amdgcn_s_setprio(1);                                       \
        _Pragma("unroll")                                                    \
        for (int m = 0; m < 4; ++m)                                          \
            _Pragma("unroll")                                                \
            for (int n = 0; n < 4; ++n) {                                    \
                acc[m][n] = MFMA_BF16(a_[m][0], b_[n][0], acc[m][n], 0, 0, 0); \
                acc[m][n] = MFMA_BF16(a_[m][1], b_[n][1], acc[m][n], 0, 0, 0); \
            }                                                                \
        __builtin_amdgcn_s_setprio(0);                                       \
        if ((kt) + 2 < NT)                                                   \
            asm volatile("s_waitcnt vmcnt(6)" ::: "memory");                 \
        else if ((kt) + 1 < NT)                                              \
            asm volatile("s_waitcnt vmcnt(0)" ::: "memory");                 \
        __builtin_amdgcn_s_barrier();                                        \
    } while (0)

    // prologue: stage tiles 0,1 (12 gloads); wait tile 0 (oldest 6)
    STAGE(0, 0);
    STAGE(1, 1);
    asm volatile("s_waitcnt vmcnt(6)" ::: "memory");
    __builtin_amdgcn_s_barrier();

    for (int kt = 0; kt < NT; kt += 3) {     // NT = 33 = 3*11
        TILE(0, 2, kt);
        TILE(1, 0, kt + 1);
        TILE(2, 1, kt + 2);
    }
#undef TILE
#undef STAGE

    // Epilogue: store C (pre-BN) + fused column sum/sumsq partials.
    // C/D layout col=lane&15, row=(lane>>4)*4+reg (m89/m91 verified).
    const int rlo = kq * 4;
#pragma unroll
    for (int n = 0; n < 4; ++n) {
        const int col = bn + wc * 64 + n * 16 + cl;
        float s = 0.f, q = 0.f;
#pragma unroll
        for (int m = 0; m < 4; ++m) {
            const int rowb = bm + wr * 64 + m * 16 + rlo;
#pragma unroll
            for (int r2 = 0; r2 < 4; ++r2) {
                float v = acc[m][n][r2];
                C[(size_t)(rowb + r2) * ODIM + col] = v;
                s += v; q += v * v;
            }
        }
        s += __shfl_xor(s, 16); s += __shfl_xor(s, 32);
        q += __shfl_xor(q, 16); q += __shfl_xor(q, 32);
        if (lane < 16) {
            atomicAdd(&sums[col], s);
            atomicAdd(&sums[ODIM + col], q);
        }
    }
}

// ---------------------------------------------------------------------------
// Kernel 4: BN apply with inline finalize (2048 blocks, 4 rows/thread).
// ---------------------------------------------------------------------------
__global__ __launch_bounds__(256) void bn_apply(float* __restrict__ C,
                                                const float* __restrict__ sums,
                                                const float* __restrict__ gamma,
                                                const float* __restrict__ beta) {
    const int g = blockIdx.x * 256 + threadIdx.x;
    const int c4 = g & (ODIM / 4 - 1);
    const int row0 = g >> 8;                        // 0..2047
    const float inv = 1.0f / (float)NROWS;
    float4 sc, sh;
    {
        float4 s0 = reinterpret_cast<const float4*>(sums)[c4];
        float4 q0 = reinterpret_cast<const float4*>(sums + ODIM)[c4];
        float4 gm = reinterpret_cast<const float4*>(gamma)[c4];
        float4 bt = reinterpret_cast<const float4*>(beta)[c4];
        float m, v;
        m = s0.x * inv; v = q0.x * inv - m * m; sc.x = gm.x * rsqrtf(v + BN_EPS); sh.x = bt.x - m * sc.x;
        m = s0.y * inv; v = q0.y * inv - m * m; sc.y = gm.y * rsqrtf(v + BN_EPS); sh.y = bt.y - m * sc.y;
        m = s0.z * inv; v = q0.z * inv - m * m; sc.z = gm.z * rsqrtf(v + BN_EPS); sh.z = bt.z - m * sc.z;
        m = s0.w * inv; v = q0.w * inv - m * m; sc.w = gm.w * rsqrtf(v + BN_EPS); sh.w = bt.w - m * sc.w;
    }
#pragma unroll
    for (int r = 0; r < 4; ++r) {
        const size_t i = (size_t)(row0 + r * 2048) * (ODIM / 4) + c4;
        float4 v = reinterpret_cast<const float4*>(C)[i];
        v.x = v.x * sc.x + sh.x;
        v.y = v.y * sc.y + sh.y;
        v.z = v.z * sc.z + sh.z;
        v.w = v.w * sc.w + sh.w;
        reinterpret_cast<float4*>(C)[i] = v;
    }
}

// ---------------------------------------------------------------------------
extern "C" void kernel_launch(void* const* d_in, const int* in_sizes, int n_in,
                              void* d_out, int out_size, void* d_ws, size_t ws_size,
                              hipStream_t stream) {
    const float* X     = (const float*)d_in[0];
    const float* Wz    = (const float*)d_in[1];
    const float* theta = (const float*)d_in[2];
    const float* Wa    = (const float*)d_in[3];
    const float* gamma = (const float*)d_in[5];
    const float* beta  = (const float*)d_in[6];
    float* out = (float*)d_out;

    char* ws = (char*)d_ws;
    float* sums = (float*)ws;                                        // 2*1024 f32
    short* Xa = (short*)(ws + 16384);                                // 8192*2112 bf16
    short* Aw = (short*)(ws + 16384 + (size_t)NROWS * KA * 2);       // 1024*2112 bf16
    float* partials = (float*)(ws + 16384 + (size_t)NROWS * KA * 2
                                        + (size_t)ODIM * KA * 2);    // 8*1024*64 f32

    a1a2_kern<<<A1A2_TOT, 256, 0, stream>>>(Aw, Wa, Wz, theta, partials, sums);
    conv_kern<<<CONV_NB + RED_NB, 256, 0, stream>>>(X, Xa, partials, Aw);
    gemm_kern<<<dim3(NROWS / GBM, ODIM / GBN), 512, 0, stream>>>(Xa, Aw, out, sums);
    bn_apply<<<NROWS / 4 * ODIM / 4 / 256, 256, 0, stream>>>(out, sums, gamma, beta);
}